// Round 16
// baseline (183.573 us; speedup 1.0000x reference)
//
#include <hip/hip_runtime.h>
#include <math.h>

// Problem constants: N=2, C=256, H=W=48, HID=10, P=7
constexpr int NB_ = 2;
constexpr int C_  = 256;
constexpr int HW_ = 2304;   // 48*48

typedef float f32x4 __attribute__((ext_vector_type(4)));
typedef short short8 __attribute__((ext_vector_type(8)));

__device__ __forceinline__ float coordval(int c, int k) {
  int y = k / 48, x = k - y * 48;
  switch (c) {
    case 0: return x * (1.f/24.f) - 1.f;
    case 1: return y * (1.f/24.f) - 1.f;
    case 2: return (x + 1) * (1.f/24.f) - 1.f;
    case 3: return (y + 1) * (1.f/24.f) - 1.f;
    case 4: return (x + 0.5f) * (1.f/24.f) - 1.f;
    case 5: return (y + 0.5f) * (1.f/24.f) - 1.f;
    default: return 1.f/48.f;
  }
}

__device__ __forceinline__ float sigmoidf_(float x) { return 1.f / (1.f + expf(-x)); }
__device__ __forceinline__ unsigned short f2bf(float f) {
  unsigned int u = __float_as_uint(f);
  unsigned int r = (u + 0x7FFFu + ((u >> 16) & 1u)) >> 16;
  return (unsigned short)r;
}
__device__ __forceinline__ float bf2f(unsigned short h) {
  return __uint_as_float(((unsigned int)h) << 16);
}

// ===========================================================================
// FA: fused independent pre-kernels.  HEAVY BLOCKS FIRST (tail-fill with wbf):
//   bid [0,384)       : softmax+hu (12 pairs x 32 channel-groups of 8)
//   bid [384,456)     : xbf transpose
//   bid [456,564)     : yhv conv half
//   bid [564,2612)    : weight transform (2048 tiny blocks, backfill)
// ===========================================================================
__device__ __forceinline__ void xbf_impl(int bid, char* smem,
    const float* __restrict__ xp, unsigned short* __restrict__ xbf)
{
  float (*xt)[65] = (float(*)[65])smem;
  int t = threadIdx.x;
  int px0 = bid * 64;
  int n = px0 / HW_, k0 = px0 - n * HW_;
  for (int cb = 0; cb < 4; ++cb) {
    __syncthreads();
    for (int i = t; i < 4096; i += 256) {
      int cl = i >> 6, pxl = i & 63;
      xt[cl][pxl] = xp[((size_t)(n * C_ + cb * 64 + cl)) * HW_ + k0 + pxl];
    }
    __syncthreads();
    for (int i = t; i < 4096; i += 256) {
      int pxl = i >> 6, cl = i & 63;
      xbf[((size_t)(n * HW_ + k0 + pxl)) * 256 + cb * 64 + cl] = f2bf(xt[cl][pxl]);
    }
  }
}

__device__ __forceinline__ void wbf_impl(int bid, char* smem,
    const float* __restrict__ ctx_w1, const float* __restrict__ du_a1,
    const float* __restrict__ dl_a1,
    unsigned short* __restrict__ wt, float* __restrict__ w0)
{
  float* sl = (float*)smem;
  int inst = bid >> 8, oc = bid & 255;
  const float* src = (inst < 6) ? (ctx_w1 + (size_t)inst * 256 * 2313)
                   : (inst == 6 ? du_a1 : dl_a1);
  src += (size_t)oc * 2313;
  int t = threadIdx.x;
  for (int i = t; i < 2313; i += 256) sl[i] = src[i];
  __syncthreads();
  int mf = oc >> 4, lr = oc & 15;
  for (int i = t; i < 288; i += 256) {
    int pos = i / 32; int rest = i - pos * 32;
    int chunk = rest >> 2, lg = rest & 3;
    short8 v;
    #pragma unroll
    for (int j = 0; j < 8; ++j) {
      int c = chunk * 32 + lg * 8 + j;
      v[j] = (short)f2bf(sl[(size_t)(c + 1) * 9 + pos]);
    }
    size_t addr = ((((size_t)(inst * 9 + pos) * 8 + chunk) * 16 + mf) << 9)
                  + (size_t)(lg * 16 + lr) * 8;
    *(short8*)(wt + addr) = v;
  }
  if (t < 9) w0[((size_t)inst * 256 + oc) * 9 + t] = sl[t];
}

// 8 channels per block: pair(12) x cb(32)
__device__ __forceinline__ void smhuc_impl(int bid, char* smem,
    const float* __restrict__ xp, const float* __restrict__ p_att,
    float* __restrict__ hu_ws)
{
  float* na  = (float*)smem;            // 2304
  float* red = (float*)(smem + 9216);   // 16
  int cb = bid & 31; int pair = bid >> 5;
  int n = pair % NB_;
  int t = threadIdx.x;
  const float* att = p_att + (size_t)(NB_ + pair) * HW_;

  float m = -1e30f;
  for (int k = t; k < HW_; k += 256) m = fmaxf(m, att[k]);
  #pragma unroll
  for (int off = 32; off > 0; off >>= 1) m = fmaxf(m, __shfl_down(m, off, 64));
  if ((t & 63) == 0) red[t >> 6] = m;
  __syncthreads();
  if (t == 0) { float mm = red[0]; for (int w = 1; w < 4; ++w) mm = fmaxf(mm, red[w]); red[0] = mm; }
  __syncthreads();
  m = red[0];
  float s = 0.f;
  for (int k = t; k < HW_; k += 256) s += expf(att[k] - m);
  #pragma unroll
  for (int off = 32; off > 0; off >>= 1) s += __shfl_down(s, off, 64);
  if ((t & 63) == 0) red[8 + (t >> 6)] = s;
  __syncthreads();
  if (t == 0) { float ss = 0; for (int w = 0; w < 4; ++w) ss += red[8 + w]; red[8] = ss; }
  __syncthreads();
  float inv = 1.f / red[8];
  for (int k = t; k < HW_; k += 256) na[k] = expf(att[k] - m) * inv;
  __syncthreads();

  int wv = t >> 6, l = t & 63;
  #pragma unroll
  for (int cq = 0; cq < 2; ++cq) {
    int c = cb * 8 + wv * 2 + cq;
    const float* x = xp + (size_t)(n * C_ + c) * HW_;
    float a = 0.f;
    for (int k = l; k < HW_; k += 64) a = fmaf(x[k], na[k], a);
    #pragma unroll
    for (int off = 32; off > 0; off >>= 1) a += __shfl_down(a, off, 64);
    if (l == 0) hu_ws[(size_t)pair * 256 + c] = a;
  }
}

__device__ __forceinline__ void yhv_impl(int bid, char* smem,
    const float* __restrict__ p_nodes, const float* __restrict__ dp_r1,
    float* __restrict__ yhv_ws)
{
  float (*xt)[18][20] = (float(*)[18][20])smem;        // 10*18*20 = 3600 f
  float* wl = (float*)(smem + 14400);                  // 900 f
  int tile = bid % 9; bid /= 9;
  int n = bid % NB_;  int v = bid / NB_;
  int ty0 = (tile / 3) * 16, tx0 = (tile % 3) * 16;
  int t = threadIdx.x;
  for (int i = t; i < 900; i += 256) {
    int d = i / 90; int rest = i - d * 90; int ic = rest / 9; int pos = rest - ic * 9;
    wl[i] = dp_r1[(d * 20 + 10 + ic) * 9 + pos];
  }
  for (int i = t; i < 10 * 324; i += 256) {
    int d = i / 324; int rr = (i % 324) / 18; int cc = i % 18;
    int gy = ty0 + rr - 1, gx = tx0 + cc - 1;
    float val = 0.f;
    if (gy >= 0 && gy < 48 && gx >= 0 && gx < 48)
      val = p_nodes[((size_t)(v * NB_ + n) * 10 + d) * HW_ + gy * 48 + gx];
    xt[d][rr][cc] = val;
  }
  __syncthreads();
  int rr = t >> 4, cc = t & 15;
  int k = (ty0 + rr) * 48 + tx0 + cc;
  float y[10];
  #pragma unroll
  for (int d = 0; d < 10; ++d) y[d] = 0.f;
  for (int ic = 0; ic < 10; ++ic)
    #pragma unroll
    for (int kh = 0; kh < 3; ++kh)
      #pragma unroll
      for (int kw = 0; kw < 3; ++kw) {
        float xv = xt[ic][rr + kh][cc + kw];
        #pragma unroll
        for (int d = 0; d < 10; ++d)
          y[d] = fmaf(wl[(d * 10 + ic) * 9 + kh * 3 + kw], xv, y[d]);
      }
  #pragma unroll
  for (int d = 0; d < 10; ++d)
    yhv_ws[((size_t)(v * NB_ + n) * 10 + d) * HW_ + k] = y[d];
}

__global__ __launch_bounds__(256) void k_fa(
    const float* __restrict__ xp, unsigned short* __restrict__ xbf,
    const float* __restrict__ ctx_w1, const float* __restrict__ du_a1,
    const float* __restrict__ dl_a1,
    unsigned short* __restrict__ wt, float* __restrict__ w0,
    const float* __restrict__ p_att, float* __restrict__ hu_ws,
    const float* __restrict__ p_nodes, const float* __restrict__ dp_r1,
    float* __restrict__ yhv_ws)
{
  __shared__ __align__(16) char smem[18432];
  int bid = blockIdx.x;
  if (bid < 384)       smhuc_impl(bid, smem, xp, p_att, hu_ws);
  else if (bid < 456)  xbf_impl(bid - 384, smem, xp, xbf);
  else if (bid < 564)  yhv_impl(bid - 456, smem, p_nodes, dp_r1, yhv_ws);
  else                 wbf_impl(bid - 564, smem, ctx_w1, du_a1, dl_a1, wt, w0);
}

// ===========================================================================
// FB: bid [0,12) qdot; bid [12,84) rpx
// ===========================================================================
__device__ __forceinline__ void qdot_impl(int pair, char* smem,
    const float* __restrict__ p_att, const float* __restrict__ hu_ws,
    const float* __restrict__ dc_q_w, const float* __restrict__ dc_q_b,
    const float* __restrict__ dc_p_w, float* __restrict__ qdot)
{
  float* na  = (float*)smem;
  float* red = (float*)(smem + 9216);
  float* co  = (float*)(smem + 9280);
  float* hu  = (float*)(smem + 9312);
  float* ql  = (float*)(smem + 10336);
  int t = threadIdx.x;
  const float* att = p_att + (size_t)(NB_ + pair) * HW_;

  float m = -1e30f;
  for (int k = t; k < HW_; k += 256) m = fmaxf(m, att[k]);
  #pragma unroll
  for (int off = 32; off > 0; off >>= 1) m = fmaxf(m, __shfl_down(m, off, 64));
  if ((t & 63) == 0) red[t >> 6] = m;
  __syncthreads();
  if (t == 0) { float mm = red[0]; for (int w = 1; w < 4; ++w) mm = fmaxf(mm, red[w]); red[0] = mm; }
  __syncthreads();
  m = red[0];
  float s = 0.f;
  for (int k = t; k < HW_; k += 256) s += expf(att[k] - m);
  #pragma unroll
  for (int off = 32; off > 0; off >>= 1) s += __shfl_down(s, off, 64);
  if ((t & 63) == 0) red[8 + (t >> 6)] = s;
  __syncthreads();
  if (t == 0) { float ss = 0; for (int w = 0; w < 4; ++w) ss += red[8 + w]; red[8] = ss; }
  __syncthreads();
  float inv = 1.f / red[8];
  for (int k = t; k < HW_; k += 256) na[k] = expf(att[k] - m) * inv;
  hu[t] = hu_ws[(size_t)pair * 256 + t];
  __syncthreads();

  int wv = t >> 6, l = t & 63;
  #pragma unroll
  for (int q = 0; q < 2; ++q) {
    int cc = wv * 2 + q;
    float a = 0.f;
    for (int k = l; k < HW_; k += 64) a = fmaf(coordval(cc, k), na[k], a);
    #pragma unroll
    for (int off = 32; off > 0; off >>= 1) a += __shfl_down(a, off, 64);
    if (l == 0) co[cc] = a;
  }
  __syncthreads();
  if (t < 64) {
    float a = dc_q_b[t];
    const float* wr = dc_q_w + (size_t)t * 264;
    for (int c = 0; c < 256; ++c) a = fmaf(wr[c], hu[c], a);
    #pragma unroll
    for (int c = 0; c < 8; ++c) a = fmaf(wr[256 + c], co[c], a);
    ql[t] = fmaxf(a, 0.f) * dc_p_w[t];
  }
  __syncthreads();
  if (t == 0) {
    float a = 0.f;
    for (int d = 0; d < 64; ++d) a += ql[d];
    qdot[pair] = a;
  }
}

__device__ __forceinline__ void rpx_impl(int bid, char* smem,
    const unsigned short* __restrict__ xbf, const float* __restrict__ dp_proj,
    float* __restrict__ rpx)
{
  float* pj   = (float*)smem;            // 2560
  float* part = (float*)(smem + 10240);  // 1920
  int t = threadIdx.x;
  for (int i = t; i < 2560; i += 256) {
    int d = i >> 8, c = i & 255;
    pj[c * 10 + d] = dp_proj[i];
  }
  __syncthreads();
  int lane = t & 63, q = t >> 6;
  int px = bid * 64 + lane;
  const unsigned short* xr = xbf + (size_t)px * 256;
  float acc[10];
  #pragma unroll
  for (int d = 0; d < 10; ++d) acc[d] = 0.f;
  for (int c8 = q * 8; c8 < q * 8 + 8; ++c8) {
    short8 v = *(const short8*)(xr + c8 * 8);
    #pragma unroll
    for (int j = 0; j < 8; ++j) {
      float f = bf2f((unsigned short)v[j]);
      const float* pc = &pj[(c8 * 8 + j) * 10];
      #pragma unroll
      for (int d = 0; d < 10; ++d) acc[d] = fmaf(pc[d], f, acc[d]);
    }
  }
  if (q) {
    #pragma unroll
    for (int d = 0; d < 10; ++d) part[((q - 1) * 64 + lane) * 10 + d] = acc[d];
  }
  __syncthreads();
  if (t < 64) {
    int p2 = bid * 64 + t;
    int n = p2 / HW_, k = p2 - n * HW_;
    #pragma unroll
    for (int d = 0; d < 10; ++d) {
      float s = acc[d] + part[t * 10 + d] + part[(64 + t) * 10 + d] + part[(128 + t) * 10 + d];
      rpx[((size_t)(n * 10 + d)) * HW_ + k] = fmaxf(s, 0.f);
    }
  }
}

__global__ __launch_bounds__(256) void k_fb(
    const float* __restrict__ p_att, const float* __restrict__ hu_ws,
    const float* __restrict__ dc_q_w, const float* __restrict__ dc_q_b,
    const float* __restrict__ dc_p_w, float* __restrict__ qdot,
    const unsigned short* __restrict__ xbf, const float* __restrict__ dp_proj,
    float* __restrict__ rpx)
{
  __shared__ __align__(16) char smem[18432];
  int bid = blockIdx.x;
  if (bid < 12) qdot_impl(bid, smem, p_att, hu_ws, dc_q_w, dc_q_b, dc_p_w, qdot);
  else          rpx_impl(bid - 12, smem, xbf, dp_proj, rpx);
}

// ===========================================================================
// K1: keydot via MFMA + fused dep_att epilogue (unchanged)
// ===========================================================================
__global__ __launch_bounds__(256) void k_keymma(
    const unsigned short* __restrict__ xbf, const float* __restrict__ dc_k_w,
    const float* __restrict__ dc_k_b, const float* __restrict__ dc_p_w,
    const float* __restrict__ qdot, const float* __restrict__ dc_p_b,
    const float* __restrict__ p_att, float* __restrict__ dep_att)
{
  __shared__ unsigned short wlf[64 * 296];
  __shared__ unsigned short xl[64 * 40];
  int t = threadIdx.x;
  for (int i = t; i < 64 * 264; i += 256) {
    int d = i / 264, c = i - d * 264;
    wlf[d * 296 + c] = f2bf(dc_k_w[i]);
  }
  for (int i = t; i < 64 * 32; i += 256) {
    int d = i >> 5, c = 264 + (i & 31);
    wlf[d * 296 + c] = 0;
  }
  int px0 = blockIdx.x * 64;
  int w = t >> 6, l = t & 63;
  int lr = l & 15, lg = l >> 4;

  f32x4 acc[4];
  #pragma unroll
  for (int mi = 0; mi < 4; ++mi) acc[mi] = (f32x4){0.f,0.f,0.f,0.f};

  for (int ch = 0; ch < 9; ++ch) {
    __syncthreads();
    {
      int i = t;
      int pxl = i >> 2, q = i & 3;
      int px = px0 + pxl, n = px / HW_, k = px - n * HW_;
      int c0 = ch * 32 + q * 8;
      short8 v;
      if (c0 + 7 < 256) {
        v = *(const short8*)(xbf + ((size_t)(n * HW_ + k)) * 256 + c0);
      } else {
        #pragma unroll
        for (int j = 0; j < 8; ++j) {
          int cc = c0 + j;
          float f = (cc < 256) ? bf2f(xbf[((size_t)(n * HW_ + k)) * 256 + cc])
                   : (cc < 264 ? coordval(cc - 256, k) : 0.f);
          v[j] = (short)f2bf(f);
        }
      }
      *(short8*)(xl + pxl * 40 + q * 8) = v;
    }
    __syncthreads();
    short8 bfr = *(const short8*)(xl + (w * 16 + lr) * 40 + lg * 8);
    #pragma unroll
    for (int mi = 0; mi < 4; ++mi) {
      short8 a = *(const short8*)(wlf + (mi * 16 + lr) * 296 + ch * 32 + lg * 8);
      acc[mi] = __builtin_amdgcn_mfma_f32_16x16x32_bf16(a, bfr, acc[mi], 0, 0, 0);
    }
  }

  float s = 0.f;
  #pragma unroll
  for (int mi = 0; mi < 4; ++mi)
    #pragma unroll
    for (int r = 0; r < 4; ++r) {
      int d = mi * 16 + lg * 4 + r;
      s += dc_p_w[64 + d] * fmaxf(acc[mi][r] + dc_k_b[d], 0.f);
    }
  s += __shfl_down(s, 32, 64);
  s += __shfl_down(s, 16, 64);
  if (lg == 0) {
    int px = px0 + w * 16 + lr;
    int n = px / HW_, k = px - n * HW_;
    float base = s + dc_p_b[0];
    #pragma unroll
    for (int e = 0; e < 6; ++e) {
      float energy = qdot[e * NB_ + n] + base;
      float a = sigmoidf_(energy);
      float hu = p_att[(size_t)((1 + e) * NB_ + n) * HW_ + k];
      dep_att[((size_t)(e * NB_ + n)) * HW_ + k] = a * (1.f - hu);
    }
  }
}

// ===========================================================================
// K5: fused conv+head. 768 blocks (3/CU), 256 thr = 4 waves.
// Wave = 64oc (4 m-frags) x 48px (3 n-frags): each B ds_read feeds 4 MFMA
// (was 2 with 8x32oc waves) -> per-CU LDS-pipe load halves; 12 MFMA chain
// per iter gives 2x ILP to cover A-load latency.  Tile 6y x 8x; 40KB halo.
// ===========================================================================
__global__ __launch_bounds__(256, 3) void k_convfused(
    const unsigned short* __restrict__ xbf, const unsigned short* __restrict__ wt,
    const float* __restrict__ w0, const float* __restrict__ dep_att,
    const float* __restrict__ h_att,
    const float* __restrict__ ctx_w2, const float* __restrict__ du_a2,
    const float* __restrict__ dl_a2,
    const float* __restrict__ ctx_b2, const float* __restrict__ du_a2b,
    const float* __restrict__ dl_a2b,
    float* __restrict__ out_fdep, float* __restrict__ out_du, float* __restrict__ out_dl,
    float* __restrict__ att_sm, float* __restrict__ da_u, float* __restrict__ da_l)
{
  int bid = blockIdx.x;
  int inst = bid & 7;                 // XCD-pinned
  int n = (bid >> 3) & 1;
  int tile = bid >> 4;                // 0..47
  int ty0 = (tile / 6) * 6;           // 8 tile-rows (y step 6)
  int tx0 = (tile % 6) * 8;           // 6 tile-cols (x step 8)

  __shared__ __align__(16) unsigned short xs[80 * 256];  // 40KB swizzled halo
  __shared__ float asf[80];

  const float* asrc = (inst < 6) ? dep_att + (size_t)(inst * NB_ + n) * HW_
                    : h_att + (size_t)(((inst == 6) ? 1 : 2) * NB_ + n) * HW_;
  int nd = (inst < 6) ? 5 : (inst == 6 ? 4 : 2);
  const float* w2 = (inst < 6) ? ctx_w2 + (size_t)inst * 5 * 256
                               : (inst == 6 ? du_a2 : dl_a2);

  int t = threadIdx.x;
  const unsigned short* xg = xbf + (size_t)n * HW_ * 256;

  for (int i = t; i < 2560; i += 256) {
    int row = i >> 5, q = i & 31;
    int yy = row / 10, xx = row - yy * 10;
    int gy = ty0 + yy - 1, gx = tx0 + xx - 1;
    short8 v = (short8){0,0,0,0,0,0,0,0};
    if (gy >= 0 && gy < 48 && gx >= 0 && gx < 48)
      v = *(const short8*)(xg + ((size_t)(gy * 48 + gx)) * 256 + q * 8);
    int s = q ^ (row & 7);
    *(short8*)(xs + row * 256 + s * 8) = v;
  }
  for (int i = t; i < 80; i += 256) {
    int yy = i / 10, xx = i - yy * 10;
    int gy = ty0 + yy - 1, gx = tx0 + xx - 1;
    asf[i] = (gy >= 0 && gy < 48 && gx >= 0 && gx < 48) ? asrc[gy * 48 + gx] : 0.f;
  }
  __syncthreads();

  int wm = t >> 6;                    // wave 0..3 -> oc block wm*64
  int l = t & 63;
  int lr = l & 15, lg = l >> 4;

  f32x4 acc[4][3];
  #pragma unroll
  for (int mi = 0; mi < 4; ++mi)
    #pragma unroll
    for (int nf = 0; nf < 3; ++nf) acc[mi][nf] = (f32x4){0.f,0.f,0.f,0.f};

  int rb[3];
  #pragma unroll
  for (int nf = 0; nf < 3; ++nf) {
    int p = nf * 16 + lr;
    int y = p >> 3, x = p & 7;
    rb[nf] = y * 10 + x;
  }

  const unsigned short* wta = wt + (((size_t)inst * 72 * 16) << 9)
                              + (((size_t)(wm * 4)) << 9) + (size_t)l * 8;
  short8 av[4], nv[4];
  #pragma unroll
  for (int mi = 0; mi < 4; ++mi)
    av[mi] = *(const short8*)(wta + ((size_t)mi << 9));

  for (int ch = 0; ch < 8; ++ch) {
    #pragma unroll
    for (int pos = 0; pos < 9; ++pos) {
      // prefetch next-(pos,ch) A frags
      {
        int npos = (pos == 8) ? 0 : pos + 1;
        int nch = (pos == 8) ? ((ch + 1 > 7) ? 7 : ch + 1) : ch;
        size_t ofs = ((size_t)((npos * 8 + nch) * 16)) << 9;
        #pragma unroll
        for (int mi = 0; mi < 4; ++mi)
          nv[mi] = *(const short8*)(wta + ofs + ((size_t)mi << 9));
      }
      int koff = (pos / 3) * 10 + (pos % 3);
      short8 bfr[3];
      #pragma unroll
      for (int nf = 0; nf < 3; ++nf) {
        int rowIdx = rb[nf] + koff;
        int s = (ch * 4 + lg) ^ (rowIdx & 7);
        bfr[nf] = *(const short8*)(xs + rowIdx * 256 + s * 8);
      }
      #pragma unroll
      for (int mi = 0; mi < 4; ++mi)
        #pragma unroll
        for (int nf = 0; nf < 3; ++nf)
          acc[mi][nf] = __builtin_amdgcn_mfma_f32_16x16x32_bf16(av[mi], bfr[nf], acc[mi][nf], 0, 0, 0);
      #pragma unroll
      for (int mi = 0; mi < 4; ++mi) av[mi] = nv[mi];
    }
  }

  __syncthreads();
  float* ovl = (float*)xs;
  float* w0l = ovl;                 // 2304
  float* w2l = ovl + 2304;          // 1280
  float* sred = ovl + 3584;         // 4 waves x 48 px x 5 = 960
  for (int i = t; i < 2304; i += 256) w0l[i] = w0[(size_t)inst * 2304 + i];
  for (int i = t; i < 1280; i += 256) w2l[i] = (i < nd * 256) ? w2[i] : 0.f;
  __syncthreads();

  float pd[3][5];
  #pragma unroll
  for (int nf = 0; nf < 3; ++nf)
    #pragma unroll
    for (int d = 0; d < 5; ++d) pd[nf][d] = 0.f;

  #pragma unroll
  for (int nf = 0; nf < 3; ++nf) {
    #pragma unroll
    for (int mi = 0; mi < 4; ++mi) {
      #pragma unroll
      for (int r = 0; r < 4; ++r) {
        int oc = wm * 64 + mi * 16 + lg * 4 + r;
        float v = acc[mi][nf][r];
        const float* wr = &w0l[oc * 9];
        #pragma unroll
        for (int pos = 0; pos < 9; ++pos) {
          int koff = (pos / 3) * 10 + (pos % 3);
          v = fmaf(wr[pos], asf[rb[nf] + koff], v);
        }
        v = fmaxf(v, 0.f);
        #pragma unroll
        for (int d = 0; d < 5; ++d) pd[nf][d] = fmaf(w2l[d * 256 + oc], v, pd[nf][d]);
      }
    }
  }
  #pragma unroll
  for (int nf = 0; nf < 3; ++nf)
    #pragma unroll
    for (int d = 0; d < 5; ++d) {
      float s = pd[nf][d];
      s += __shfl_down(s, 32, 64);
      s += __shfl_down(s, 16, 64);
      pd[nf][d] = s;
    }
  if (lg == 0) {
    #pragma unroll
    for (int nf = 0; nf < 3; ++nf) {
      int pxi = nf * 16 + lr;
      #pragma unroll
      for (int d = 0; d < 5; ++d)
        sred[(wm * 48 + pxi) * 5 + d] = pd[nf][d];
    }
  }
  __syncthreads();
  if (t < 48) {
    int y = t >> 3, x = t & 7;
    int gk = (ty0 + y) * 48 + tx0 + x;
    float vals[5];
    float mx = -1e30f;
    for (int d = 0; d < nd; ++d) {
      float s = 0.f;
      #pragma unroll
      for (int wq = 0; wq < 4; ++wq) s += sred[(wq * 48 + t) * 5 + d];
      s += (inst < 6) ? ctx_b2[inst * 5 + d] : (inst == 6 ? du_a2b[d] : dl_a2b[d]);
      vals[d] = s;
      mx = fmaxf(mx, s);
      if (inst < 6)       out_fdep[((size_t)(inst * NB_ + n) * 5 + d) * HW_ + gk] = s;
      else if (inst == 6) out_du[((size_t)n * 4 + d) * HW_ + gk] = s;
      else                out_dl[((size_t)n * 2 + d) * HW_ + gk] = s;
    }
    float ssum = 0.f;
    for (int d = 0; d < nd; ++d) { vals[d] = expf(vals[d] - mx); ssum += vals[d]; }
    float is = 1.f / ssum;
    for (int d = 0; d < nd; ++d) {
      float sm = vals[d] * is;
      if (inst < 6)       att_sm[((size_t)(inst * NB_ + n) * 5 + d) * HW_ + gk] = sm;
      else if (inst == 6) da_u[((size_t)n * 4 + d) * HW_ + gk] = sm;
      else                da_l[((size_t)n * 2 + d) * HW_ + gk] = sm;
    }
  }
}

// ===========================================================================
// K7b: per-edge message.  ad = asrc*dsrc precomputed once in LDS.
// ===========================================================================
__global__ __launch_bounds__(256) void k_msgs_edge(
    const float* __restrict__ att_sm, const float* __restrict__ dep_att,
    const float* __restrict__ rpx, const float* __restrict__ yhv_ws,
    const float* __restrict__ dp_r1, const float* __restrict__ dp_r2,
    const float* __restrict__ dp_r2b, float* __restrict__ msg_ws)
{
  int b = blockIdx.x;
  int tile = b % 9; b /= 9;
  int n = b % NB_;  b /= NB_;
  int ui = b % 5;   int v = b / 5;
  int u = (ui < v) ? ui : ui + 1;
  int ce = (v < u) ? v : v - 1;
  int ty0 = (tile / 3) * 16, tx0 = (tile % 3) * 16;

  __shared__ float xt[10][18][20];
  __shared__ float ad[324];
  __shared__ float wl[900];
  __shared__ float w2l[100];
  __shared__ float b2l[10];
  int t = threadIdx.x;
  for (int i = t; i < 900; i += 256) {
    int d = i / 90; int rest = i - d * 90; int ic = rest / 9; int pos = rest - ic * 9;
    wl[i] = dp_r1[(d * 20 + ic) * 9 + pos];
  }
  for (int i = t; i < 100; i += 256) w2l[i] = dp_r2[i];
  if (t < 10) b2l[t] = dp_r2b[t];

  const float* asrc = att_sm + ((size_t)(u * NB_ + n) * 5 + ce) * HW_;
  const float* dsrc = dep_att + (size_t)(u * NB_ + n) * HW_;
  for (int i = t; i < 324; i += 256) {
    int rr = i / 18, cc = i - (i / 18) * 18;
    int gy = ty0 + rr - 1, gx = tx0 + cc - 1;
    float val = 0.f;
    if (gy >= 0 && gy < 48 && gx >= 0 && gx < 48) {
      int kk = gy * 48 + gx;
      val = asrc[kk] * dsrc[kk];
    }
    ad[i] = val;
  }
  __syncthreads();
  for (int i = t; i < 10 * 324; i += 256) {
    int d = i / 324; int r = i - d * 324; int rr = r / 18; int cc = r - rr * 18;
    int gy = ty0 + rr - 1, gx = tx0 + cc - 1;
    float val = 0.f;
    if (gy >= 0 && gy < 48 && gx >= 0 && gx < 48) {
      int kk = gy * 48 + gx;
      val = ad[r] * rpx[((size_t)n * 10 + d) * HW_ + kk];
    }
    xt[d][rr][cc] = val;
  }
  __syncthreads();
  int rr = t >> 4, cc = t & 15;
  int k = (ty0 + rr) * 48 + tx0 + cc;
  float y[10];
  #pragma unroll
  for (int d = 0; d < 10; ++d) y[d] = 0.f;
  for (int ic = 0; ic < 10; ++ic)
    #pragma unroll
    for (int kh = 0; kh < 3; ++kh)
      #pragma unroll
      for (int kw = 0; kw < 3; ++kw) {
        float xv = xt[ic][rr + kh][cc + kw];
        #pragma unroll
        for (int d = 0; d < 10; ++d)
          y[d] = fmaf(wl[(d * 10 + ic) * 9 + kh * 3 + kw], xv, y[d]);
      }
  float s[10];
  #pragma unroll
  for (int d = 0; d < 10; ++d)
    s[d] = fmaxf(y[d] + yhv_ws[((size_t)(v * NB_ + n) * 10 + d) * HW_ + k], 0.f);
  #pragma unroll
  for (int d = 0; d < 10; ++d) {
    float m = b2l[d];
    #pragma unroll
    for (int j = 0; j < 10; ++j) m = fmaf(w2l[d * 10 + j], s[j], m);
    msg_ws[(((size_t)(v * 5 + ui) * NB_ + n) * 10 + d) * HW_ + k] = sigmoidf_(m);
  }
}

// ===========================================================================
// K8: parts conv + alpha*sum(msgs) + GRU (nodes 0..6).  dp = da*patt cached.
// ===========================================================================
__global__ __launch_bounds__(256) void k_parts_gru(
    const float* __restrict__ h_nodes, const float* __restrict__ p_nodes,
    const float* __restrict__ h_att,
    const float* __restrict__ da_u, const float* __restrict__ da_l,
    const float* __restrict__ du_r1, const float* __restrict__ du_r2,
    const float* __restrict__ dl_r1, const float* __restrict__ dl_r2,
    const float* __restrict__ msg_ws, const float* __restrict__ alpha,
    const float* __restrict__ gru_gw, const float* __restrict__ gru_gb,
    const float* __restrict__ gru_cw, float* __restrict__ p_new)
{
  int b = blockIdx.x;
  int tile = b % 9; b /= 9;
  int n = b % NB_;  int vp = b / NB_;   // 0..6
  int ty0 = (tile / 3) * 16, tx0 = (tile % 3) * 16;
  int t = threadIdx.x;
  int rr = t >> 4, cc = t & 15;
  int k = (ty0 + rr) * 48 + tx0 + cc;

  float x[10], h[10];

  if (vp == 0) {
    #pragma unroll
    for (int d = 0; d < 10; ++d) {
      x[d] = h_nodes[((size_t)n * 10 + d) * HW_ + k];
      h[d] = p_nodes[((size_t)n * 10 + d) * HW_ + k];
    }
  } else {
    bool isU = (vp <= 4);
    int j = isU ? vp - 1 : vp - 5;
    const float* parent = h_nodes + ((size_t)((isU ? 1 : 2) * NB_ + n) * 10) * HW_;
    const float* patt   = h_att + (size_t)((isU ? 1 : 2) * NB_ + n) * HW_;
    const float* da     = isU ? (da_u + ((size_t)n * 4 + j) * HW_) : (da_l + ((size_t)n * 2 + j) * HW_);
    const float* child  = p_nodes + (size_t)(vp * NB_ + n) * 10 * HW_;
    const float* r1 = isU ? du_r1 : dl_r1;
    const float* r2 = isU ? du_r2 : dl_r2;

    __shared__ float xt[20][18][20];
    __shared__ float dpl[324];
    __shared__ float wl[1800];
    __shared__ float w2l[100];
    for (int i = t; i < 1800; i += 256) wl[i] = r1[i];
    for (int i = t; i < 100; i += 256) w2l[i] = r2[i];
    for (int i = t; i < 324; i += 256) {
      int r2i = i / 18, c2 = i - (i / 18) * 18;
      int gy = ty0 + r2i - 1, gx = tx0 + c2 - 1;
      float val = 0.f;
      if (gy >= 0 && gy < 48 && gx >= 0 && gx < 48) {
        int kk = gy * 48 + gx;
        val = da[kk] * patt[kk];
      }
      dpl[i] = val;
    }
    __syncthreads();
    for (int i = t; i < 20 * 324; i += 256) {
      int d = i / 324; int r = i - d * 324; int r2i = r / 18; int c2 = r - r2i * 18;
      int gy = ty0 + r2i - 1, gx = tx0 + c2 - 1;
      float val = 0.f;
      if (gy >= 0 && gy < 48 && gx >= 0 && gx < 48) {
        int kk = gy * 48 + gx;
        val = (d < 10) ? parent[(size_t)d * HW_ + kk] * dpl[r]
                       : child[(size_t)(d - 10) * HW_ + kk];
      }
      xt[d][r2i][c2] = val;
    }
    __syncthreads();
    float y[10];
    #pragma unroll
    for (int d = 0; d < 10; ++d) y[d] = 0.f;
    for (int ic = 0; ic < 20; ++ic)
      #pragma unroll
      for (int kh = 0; kh < 3; ++kh)
        #pragma unroll
        for (int kw = 0; kw < 3; ++kw) {
          float xv = xt[ic][rr + kh][cc + kw];
          #pragma unroll
          for (int d = 0; d < 10; ++d)
            y[d] = fmaf(wl[(d * 20 + ic) * 9 + kh * 3 + kw], xv, y[d]);
        }
    float yr[10];
    #pragma unroll
    for (int d = 0; d < 10; ++d) yr[d] = fmaxf(y[d], 0.f);

    float al = alpha[0];
    int v = vp - 1;
    #pragma unroll
    for (int d = 0; d < 10; ++d) {
      float s = 0.f;
      #pragma unroll
      for (int jj = 0; jj < 10; ++jj) s = fmaf(w2l[d * 10 + jj], yr[jj], s);
      float parts = fmaxf(s, 0.f);
      float xs = 0.f;
      #pragma unroll
      for (int ui = 0; ui < 5; ++ui)
        xs += msg_ws[(((size_t)(v * 5 + ui) * NB_ + n) * 10 + d) * HW_ + k];
      x[d] = parts + al * xs;
      h[d] = p_nodes[((size_t)(vp * NB_ + n) * 10 + d) * HW_ + k];
    }
  }

  const float* gw = gru_gw + (size_t)vp * 40;
  const float* gb = gru_gb + (size_t)vp * 2;
  const float* cw = gru_cw + (size_t)vp * 200;
  float g0 = gb[0], g1 = gb[1];
  #pragma unroll
  for (int d = 0; d < 10; ++d) {
    g0 = fmaf(gw[d], x[d], fmaf(gw[10 + d], h[d], g0));
    g1 = fmaf(gw[20 + d], x[d], fmaf(gw[30 + d], h[d], g1));
  }
  float rg = sigmoidf_(g0);
  float ug = sigmoidf_(g1);
  #pragma unroll
  for (int d = 0; d < 10; ++d) {
    float s = 0.f;
    const float* cr = cw + d * 20;
    #pragma unroll
    for (int jj = 0; jj < 10; ++jj)
      s = fmaf(cr[jj], x[jj], fmaf(cr[10 + jj], rg * h[jj], s));
    float cn = fmaxf(s, 0.f);
    p_new[((size_t)(vp * NB_ + n) * 10 + d) * HW_ + k] = (1.f - ug) * h[d] + ug * cn;
  }
}

// ---------------------------------------------------------------------------
extern "C" void kernel_launch(void* const* d_in, const int* in_sizes, int n_in,
                              void* d_out, int out_size, void* d_ws, size_t ws_size,
                              hipStream_t stream) {
  (void)in_sizes; (void)n_in; (void)out_size; (void)ws_size;
  const float* h_nodes = (const float*)d_in[1];
  const float* p_nodes = (const float*)d_in[2];
  const float* xp      = (const float*)d_in[3];
  const float* h_att   = (const float*)d_in[4];
  const float* p_att   = (const float*)d_in[5];
  const float* dc_q_w  = (const float*)d_in[6];
  const float* dc_q_b  = (const float*)d_in[7];
  const float* dc_k_w  = (const float*)d_in[8];
  const float* dc_k_b  = (const float*)d_in[9];
  const float* dc_p_w  = (const float*)d_in[10];
  const float* dc_p_b  = (const float*)d_in[11];
  const float* ctx_w1  = (const float*)d_in[12];
  const float* ctx_w2  = (const float*)d_in[13];
  const float* ctx_b2  = (const float*)d_in[14];
  const float* du_a1   = (const float*)d_in[15];
  const float* du_a2   = (const float*)d_in[16];
  const float* du_a2b  = (const float*)d_in[17];
  const float* du_r1   = (const float*)d_in[18];
  const float* du_r2   = (const float*)d_in[19];
  const float* dl_a1   = (const float*)d_in[20];
  const float* dl_a2   = (const float*)d_in[21];
  const float* dl_a2b  = (const float*)d_in[22];
  const float* dl_r1   = (const float*)d_in[23];
  const float* dl_r2   = (const float*)d_in[24];
  const float* dp_proj = (const float*)d_in[25];
  const float* dp_r1   = (const float*)d_in[26];
  const float* dp_r2   = (const float*)d_in[27];
  const float* dp_r2b  = (const float*)d_in[28];
  const float* gru_gw  = (const float*)d_in[29];
  const float* gru_gb  = (const float*)d_in[30];
  const float* gru_cw  = (const float*)d_in[31];
  const float* alpha   = (const float*)d_in[32];

  float* ws = (float*)d_ws;
  float* qdot    = ws + 4608;          // 16
  float* dep_att = ws + 4624;          // 27648
  float* rpx     = ws + 32272;         // 46080
  float* att_sm  = ws + 78352;         // 138240
  float* da_u    = ws + 216592;        // 18432
  float* da_l    = ws + 235024;        // 9216
  float* yhv_ws  = ws + 244240;        // 276480
  float* w0      = ws + 520720;        // 18432 -> floats end at 539152
  float* hu_ws   = att_sm + 27648;     // alias (dead until k_convfused)
  unsigned short* us = (unsigned short*)(ws + 539152);
  unsigned short* xbf = us;                       // 1,179,648 shorts
  unsigned short* wt  = us + 1179648;             // 4,718,592 shorts
  float* msg_ws = (float*)(us + 5898240);         // 1,382,400 floats

  float* out      = (float*)d_out;
  float* out_pnew = out;               // 322560
  float* out_du   = out + 322560;      // 18432
  float* out_dl   = out + 340992;      // 9216
  float* out_fdep = out + 350208;      // 138240

  k_fa<<<2612, 256, 0, stream>>>(xp, xbf, ctx_w1, du_a1, dl_a1, wt, w0,
                                 p_att, hu_ws, p_nodes, dp_r1, yhv_ws);
  k_fb<<<84, 256, 0, stream>>>(p_att, hu_ws, dc_q_w, dc_q_b, dc_p_w, qdot,
                               xbf, dp_proj, rpx);
  k_keymma<<<72, 256, 0, stream>>>(xbf, dc_k_w, dc_k_b, dc_p_w,
                                   qdot, dc_p_b, p_att, dep_att);
  k_convfused<<<768, 256, 0, stream>>>(xbf, wt, w0, dep_att, h_att,
                                       ctx_w2, du_a2, dl_a2, ctx_b2, du_a2b, dl_a2b,
                                       out_fdep, out_du, out_dl, att_sm, da_u, da_l);
  k_msgs_edge<<<540, 256, 0, stream>>>(att_sm, dep_att, rpx, yhv_ws,
                                       dp_r1, dp_r2, dp_r2b, msg_ws);
  k_parts_gru<<<126, 256, 0, stream>>>(h_nodes, p_nodes, h_att, da_u, da_l,
                                       du_r1, du_r2, dl_r1, dl_r2, msg_ws, alpha,
                                       gru_gw, gru_gb, gru_cw, out_pnew);
}

// Round 17
// 176.338 us; speedup vs baseline: 1.0410x; 1.0410x over previous
//
#include <hip/hip_runtime.h>
#include <math.h>

// Problem constants: N=2, C=256, H=W=48, HID=10, P=7
constexpr int NB_ = 2;
constexpr int C_  = 256;
constexpr int HW_ = 2304;   // 48*48

typedef float f32x4 __attribute__((ext_vector_type(4)));
typedef short short8 __attribute__((ext_vector_type(8)));

__device__ __forceinline__ float coordval(int c, int k) {
  int y = k / 48, x = k - y * 48;
  switch (c) {
    case 0: return x * (1.f/24.f) - 1.f;
    case 1: return y * (1.f/24.f) - 1.f;
    case 2: return (x + 1) * (1.f/24.f) - 1.f;
    case 3: return (y + 1) * (1.f/24.f) - 1.f;
    case 4: return (x + 0.5f) * (1.f/24.f) - 1.f;
    case 5: return (y + 0.5f) * (1.f/24.f) - 1.f;
    default: return 1.f/48.f;
  }
}

__device__ __forceinline__ float sigmoidf_(float x) { return 1.f / (1.f + expf(-x)); }
__device__ __forceinline__ unsigned short f2bf(float f) {
  unsigned int u = __float_as_uint(f);
  unsigned int r = (u + 0x7FFFu + ((u >> 16) & 1u)) >> 16;
  return (unsigned short)r;
}
__device__ __forceinline__ float bf2f(unsigned short h) {
  return __uint_as_float(((unsigned int)h) << 16);
}

// ===========================================================================
// FA: fused independent pre-kernels.  HEAVY BLOCKS FIRST (tail-fill with wbf):
//   bid [0,384)       : softmax+hu (12 pairs x 32 channel-groups of 8)
//   bid [384,456)     : xbf transpose
//   bid [456,564)     : yhv conv half
//   bid [564,2612)    : weight transform (2048 tiny blocks, backfill)
// ===========================================================================
__device__ __forceinline__ void xbf_impl(int bid, char* smem,
    const float* __restrict__ xp, unsigned short* __restrict__ xbf)
{
  float (*xt)[65] = (float(*)[65])smem;
  int t = threadIdx.x;
  int px0 = bid * 64;
  int n = px0 / HW_, k0 = px0 - n * HW_;
  for (int cb = 0; cb < 4; ++cb) {
    __syncthreads();
    for (int i = t; i < 4096; i += 256) {
      int cl = i >> 6, pxl = i & 63;
      xt[cl][pxl] = xp[((size_t)(n * C_ + cb * 64 + cl)) * HW_ + k0 + pxl];
    }
    __syncthreads();
    for (int i = t; i < 4096; i += 256) {
      int pxl = i >> 6, cl = i & 63;
      xbf[((size_t)(n * HW_ + k0 + pxl)) * 256 + cb * 64 + cl] = f2bf(xt[cl][pxl]);
    }
  }
}

__device__ __forceinline__ void wbf_impl(int bid, char* smem,
    const float* __restrict__ ctx_w1, const float* __restrict__ du_a1,
    const float* __restrict__ dl_a1,
    unsigned short* __restrict__ wt, float* __restrict__ w0)
{
  float* sl = (float*)smem;
  int inst = bid >> 8, oc = bid & 255;
  const float* src = (inst < 6) ? (ctx_w1 + (size_t)inst * 256 * 2313)
                   : (inst == 6 ? du_a1 : dl_a1);
  src += (size_t)oc * 2313;
  int t = threadIdx.x;
  for (int i = t; i < 2313; i += 256) sl[i] = src[i];
  __syncthreads();
  int mf = oc >> 4, lr = oc & 15;
  for (int i = t; i < 288; i += 256) {
    int pos = i / 32; int rest = i - pos * 32;
    int chunk = rest >> 2, lg = rest & 3;
    short8 v;
    #pragma unroll
    for (int j = 0; j < 8; ++j) {
      int c = chunk * 32 + lg * 8 + j;
      v[j] = (short)f2bf(sl[(size_t)(c + 1) * 9 + pos]);
    }
    size_t addr = ((((size_t)(inst * 9 + pos) * 8 + chunk) * 16 + mf) << 9)
                  + (size_t)(lg * 16 + lr) * 8;
    *(short8*)(wt + addr) = v;
  }
  if (t < 9) w0[((size_t)inst * 256 + oc) * 9 + t] = sl[t];
}

// 8 channels per block: pair(12) x cb(32)
__device__ __forceinline__ void smhuc_impl(int bid, char* smem,
    const float* __restrict__ xp, const float* __restrict__ p_att,
    float* __restrict__ hu_ws)
{
  float* na  = (float*)smem;            // 2304
  float* red = (float*)(smem + 9216);   // 16
  int cb = bid & 31; int pair = bid >> 5;
  int n = pair % NB_;
  int t = threadIdx.x;
  const float* att = p_att + (size_t)(NB_ + pair) * HW_;

  float m = -1e30f;
  for (int k = t; k < HW_; k += 256) m = fmaxf(m, att[k]);
  #pragma unroll
  for (int off = 32; off > 0; off >>= 1) m = fmaxf(m, __shfl_down(m, off, 64));
  if ((t & 63) == 0) red[t >> 6] = m;
  __syncthreads();
  if (t == 0) { float mm = red[0]; for (int w = 1; w < 4; ++w) mm = fmaxf(mm, red[w]); red[0] = mm; }
  __syncthreads();
  m = red[0];
  float s = 0.f;
  for (int k = t; k < HW_; k += 256) s += expf(att[k] - m);
  #pragma unroll
  for (int off = 32; off > 0; off >>= 1) s += __shfl_down(s, off, 64);
  if ((t & 63) == 0) red[8 + (t >> 6)] = s;
  __syncthreads();
  if (t == 0) { float ss = 0; for (int w = 0; w < 4; ++w) ss += red[8 + w]; red[8] = ss; }
  __syncthreads();
  float inv = 1.f / red[8];
  for (int k = t; k < HW_; k += 256) na[k] = expf(att[k] - m) * inv;
  __syncthreads();

  int wv = t >> 6, l = t & 63;
  #pragma unroll
  for (int cq = 0; cq < 2; ++cq) {
    int c = cb * 8 + wv * 2 + cq;
    const float* x = xp + (size_t)(n * C_ + c) * HW_;
    float a = 0.f;
    for (int k = l; k < HW_; k += 64) a = fmaf(x[k], na[k], a);
    #pragma unroll
    for (int off = 32; off > 0; off >>= 1) a += __shfl_down(a, off, 64);
    if (l == 0) hu_ws[(size_t)pair * 256 + c] = a;
  }
}

__device__ __forceinline__ void yhv_impl(int bid, char* smem,
    const float* __restrict__ p_nodes, const float* __restrict__ dp_r1,
    float* __restrict__ yhv_ws)
{
  float (*xt)[18][20] = (float(*)[18][20])smem;        // 10*18*20 = 3600 f
  float* wl = (float*)(smem + 14400);                  // 900 f
  int tile = bid % 9; bid /= 9;
  int n = bid % NB_;  int v = bid / NB_;
  int ty0 = (tile / 3) * 16, tx0 = (tile % 3) * 16;
  int t = threadIdx.x;
  for (int i = t; i < 900; i += 256) {
    int d = i / 90; int rest = i - d * 90; int ic = rest / 9; int pos = rest - ic * 9;
    wl[i] = dp_r1[(d * 20 + 10 + ic) * 9 + pos];
  }
  for (int i = t; i < 10 * 324; i += 256) {
    int d = i / 324; int rr = (i % 324) / 18; int cc = i % 18;
    int gy = ty0 + rr - 1, gx = tx0 + cc - 1;
    float val = 0.f;
    if (gy >= 0 && gy < 48 && gx >= 0 && gx < 48)
      val = p_nodes[((size_t)(v * NB_ + n) * 10 + d) * HW_ + gy * 48 + gx];
    xt[d][rr][cc] = val;
  }
  __syncthreads();
  int rr = t >> 4, cc = t & 15;
  int k = (ty0 + rr) * 48 + tx0 + cc;
  float y[10];
  #pragma unroll
  for (int d = 0; d < 10; ++d) y[d] = 0.f;
  for (int ic = 0; ic < 10; ++ic)
    #pragma unroll
    for (int kh = 0; kh < 3; ++kh)
      #pragma unroll
      for (int kw = 0; kw < 3; ++kw) {
        float xv = xt[ic][rr + kh][cc + kw];
        #pragma unroll
        for (int d = 0; d < 10; ++d)
          y[d] = fmaf(wl[(d * 10 + ic) * 9 + kh * 3 + kw], xv, y[d]);
      }
  #pragma unroll
  for (int d = 0; d < 10; ++d)
    yhv_ws[((size_t)(v * NB_ + n) * 10 + d) * HW_ + k] = y[d];
}

__global__ __launch_bounds__(256) void k_fa(
    const float* __restrict__ xp, unsigned short* __restrict__ xbf,
    const float* __restrict__ ctx_w1, const float* __restrict__ du_a1,
    const float* __restrict__ dl_a1,
    unsigned short* __restrict__ wt, float* __restrict__ w0,
    const float* __restrict__ p_att, float* __restrict__ hu_ws,
    const float* __restrict__ p_nodes, const float* __restrict__ dp_r1,
    float* __restrict__ yhv_ws)
{
  __shared__ __align__(16) char smem[18432];
  int bid = blockIdx.x;
  if (bid < 384)       smhuc_impl(bid, smem, xp, p_att, hu_ws);
  else if (bid < 456)  xbf_impl(bid - 384, smem, xp, xbf);
  else if (bid < 564)  yhv_impl(bid - 456, smem, p_nodes, dp_r1, yhv_ws);
  else                 wbf_impl(bid - 564, smem, ctx_w1, du_a1, dl_a1, wt, w0);
}

// ===========================================================================
// FB: bid [0,12) qdot; bid [12,84) rpx
// ===========================================================================
__device__ __forceinline__ void qdot_impl(int pair, char* smem,
    const float* __restrict__ p_att, const float* __restrict__ hu_ws,
    const float* __restrict__ dc_q_w, const float* __restrict__ dc_q_b,
    const float* __restrict__ dc_p_w, float* __restrict__ qdot)
{
  float* na  = (float*)smem;
  float* red = (float*)(smem + 9216);
  float* co  = (float*)(smem + 9280);
  float* hu  = (float*)(smem + 9312);
  float* ql  = (float*)(smem + 10336);
  int t = threadIdx.x;
  const float* att = p_att + (size_t)(NB_ + pair) * HW_;

  float m = -1e30f;
  for (int k = t; k < HW_; k += 256) m = fmaxf(m, att[k]);
  #pragma unroll
  for (int off = 32; off > 0; off >>= 1) m = fmaxf(m, __shfl_down(m, off, 64));
  if ((t & 63) == 0) red[t >> 6] = m;
  __syncthreads();
  if (t == 0) { float mm = red[0]; for (int w = 1; w < 4; ++w) mm = fmaxf(mm, red[w]); red[0] = mm; }
  __syncthreads();
  m = red[0];
  float s = 0.f;
  for (int k = t; k < HW_; k += 256) s += expf(att[k] - m);
  #pragma unroll
  for (int off = 32; off > 0; off >>= 1) s += __shfl_down(s, off, 64);
  if ((t & 63) == 0) red[8 + (t >> 6)] = s;
  __syncthreads();
  if (t == 0) { float ss = 0; for (int w = 0; w < 4; ++w) ss += red[8 + w]; red[8] = ss; }
  __syncthreads();
  float inv = 1.f / red[8];
  for (int k = t; k < HW_; k += 256) na[k] = expf(att[k] - m) * inv;
  hu[t] = hu_ws[(size_t)pair * 256 + t];
  __syncthreads();

  int wv = t >> 6, l = t & 63;
  #pragma unroll
  for (int q = 0; q < 2; ++q) {
    int cc = wv * 2 + q;
    float a = 0.f;
    for (int k = l; k < HW_; k += 64) a = fmaf(coordval(cc, k), na[k], a);
    #pragma unroll
    for (int off = 32; off > 0; off >>= 1) a += __shfl_down(a, off, 64);
    if (l == 0) co[cc] = a;
  }
  __syncthreads();
  if (t < 64) {
    float a = dc_q_b[t];
    const float* wr = dc_q_w + (size_t)t * 264;
    for (int c = 0; c < 256; ++c) a = fmaf(wr[c], hu[c], a);
    #pragma unroll
    for (int c = 0; c < 8; ++c) a = fmaf(wr[256 + c], co[c], a);
    ql[t] = fmaxf(a, 0.f) * dc_p_w[t];
  }
  __syncthreads();
  if (t == 0) {
    float a = 0.f;
    for (int d = 0; d < 64; ++d) a += ql[d];
    qdot[pair] = a;
  }
}

__device__ __forceinline__ void rpx_impl(int bid, char* smem,
    const unsigned short* __restrict__ xbf, const float* __restrict__ dp_proj,
    float* __restrict__ rpx)
{
  float* pj   = (float*)smem;            // 2560
  float* part = (float*)(smem + 10240);  // 1920
  int t = threadIdx.x;
  for (int i = t; i < 2560; i += 256) {
    int d = i >> 8, c = i & 255;
    pj[c * 10 + d] = dp_proj[i];
  }
  __syncthreads();
  int lane = t & 63, q = t >> 6;
  int px = bid * 64 + lane;
  const unsigned short* xr = xbf + (size_t)px * 256;
  float acc[10];
  #pragma unroll
  for (int d = 0; d < 10; ++d) acc[d] = 0.f;
  for (int c8 = q * 8; c8 < q * 8 + 8; ++c8) {
    short8 v = *(const short8*)(xr + c8 * 8);
    #pragma unroll
    for (int j = 0; j < 8; ++j) {
      float f = bf2f((unsigned short)v[j]);
      const float* pc = &pj[(c8 * 8 + j) * 10];
      #pragma unroll
      for (int d = 0; d < 10; ++d) acc[d] = fmaf(pc[d], f, acc[d]);
    }
  }
  if (q) {
    #pragma unroll
    for (int d = 0; d < 10; ++d) part[((q - 1) * 64 + lane) * 10 + d] = acc[d];
  }
  __syncthreads();
  if (t < 64) {
    int p2 = bid * 64 + t;
    int n = p2 / HW_, k = p2 - n * HW_;
    #pragma unroll
    for (int d = 0; d < 10; ++d) {
      float s = acc[d] + part[t * 10 + d] + part[(64 + t) * 10 + d] + part[(128 + t) * 10 + d];
      rpx[((size_t)(n * 10 + d)) * HW_ + k] = fmaxf(s, 0.f);
    }
  }
}

__global__ __launch_bounds__(256) void k_fb(
    const float* __restrict__ p_att, const float* __restrict__ hu_ws,
    const float* __restrict__ dc_q_w, const float* __restrict__ dc_q_b,
    const float* __restrict__ dc_p_w, float* __restrict__ qdot,
    const unsigned short* __restrict__ xbf, const float* __restrict__ dp_proj,
    float* __restrict__ rpx)
{
  __shared__ __align__(16) char smem[18432];
  int bid = blockIdx.x;
  if (bid < 12) qdot_impl(bid, smem, p_att, hu_ws, dc_q_w, dc_q_b, dc_p_w, qdot);
  else          rpx_impl(bid - 12, smem, xbf, dp_proj, rpx);
}

// ===========================================================================
// K1: keydot via MFMA + fused dep_att epilogue (unchanged)
// ===========================================================================
__global__ __launch_bounds__(256) void k_keymma(
    const unsigned short* __restrict__ xbf, const float* __restrict__ dc_k_w,
    const float* __restrict__ dc_k_b, const float* __restrict__ dc_p_w,
    const float* __restrict__ qdot, const float* __restrict__ dc_p_b,
    const float* __restrict__ p_att, float* __restrict__ dep_att)
{
  __shared__ unsigned short wlf[64 * 296];
  __shared__ unsigned short xl[64 * 40];
  int t = threadIdx.x;
  for (int i = t; i < 64 * 264; i += 256) {
    int d = i / 264, c = i - d * 264;
    wlf[d * 296 + c] = f2bf(dc_k_w[i]);
  }
  for (int i = t; i < 64 * 32; i += 256) {
    int d = i >> 5, c = 264 + (i & 31);
    wlf[d * 296 + c] = 0;
  }
  int px0 = blockIdx.x * 64;
  int w = t >> 6, l = t & 63;
  int lr = l & 15, lg = l >> 4;

  f32x4 acc[4];
  #pragma unroll
  for (int mi = 0; mi < 4; ++mi) acc[mi] = (f32x4){0.f,0.f,0.f,0.f};

  for (int ch = 0; ch < 9; ++ch) {
    __syncthreads();
    {
      int i = t;
      int pxl = i >> 2, q = i & 3;
      int px = px0 + pxl, n = px / HW_, k = px - n * HW_;
      int c0 = ch * 32 + q * 8;
      short8 v;
      if (c0 + 7 < 256) {
        v = *(const short8*)(xbf + ((size_t)(n * HW_ + k)) * 256 + c0);
      } else {
        #pragma unroll
        for (int j = 0; j < 8; ++j) {
          int cc = c0 + j;
          float f = (cc < 256) ? bf2f(xbf[((size_t)(n * HW_ + k)) * 256 + cc])
                   : (cc < 264 ? coordval(cc - 256, k) : 0.f);
          v[j] = (short)f2bf(f);
        }
      }
      *(short8*)(xl + pxl * 40 + q * 8) = v;
    }
    __syncthreads();
    short8 bfr = *(const short8*)(xl + (w * 16 + lr) * 40 + lg * 8);
    #pragma unroll
    for (int mi = 0; mi < 4; ++mi) {
      short8 a = *(const short8*)(wlf + (mi * 16 + lr) * 296 + ch * 32 + lg * 8);
      acc[mi] = __builtin_amdgcn_mfma_f32_16x16x32_bf16(a, bfr, acc[mi], 0, 0, 0);
    }
  }

  float s = 0.f;
  #pragma unroll
  for (int mi = 0; mi < 4; ++mi)
    #pragma unroll
    for (int r = 0; r < 4; ++r) {
      int d = mi * 16 + lg * 4 + r;
      s += dc_p_w[64 + d] * fmaxf(acc[mi][r] + dc_k_b[d], 0.f);
    }
  s += __shfl_down(s, 32, 64);
  s += __shfl_down(s, 16, 64);
  if (lg == 0) {
    int px = px0 + w * 16 + lr;
    int n = px / HW_, k = px - n * HW_;
    float base = s + dc_p_b[0];
    #pragma unroll
    for (int e = 0; e < 6; ++e) {
      float energy = qdot[e * NB_ + n] + base;
      float a = sigmoidf_(energy);
      float hu = p_att[(size_t)((1 + e) * NB_ + n) * HW_ + k];
      dep_att[((size_t)(e * NB_ + n)) * HW_ + k] = a * (1.f - hu);
    }
  }
}

// ===========================================================================
// K5: fused conv+head. 768 blocks (3/CU), 512 thr = 8 waves.  (R15 config —
// measured best: 58.2us.  R16's 4x64oc variant regressed: 3 waves/SIMD lost
// more latency hiding than the halved LDS-pipe load gained.)
// Tile 6y x 8x (48px), conflict-free B reads; 40KB halo; 1-deep A prefetch.
// ===========================================================================
__global__ __launch_bounds__(512, 4) void k_convfused(
    const unsigned short* __restrict__ xbf, const unsigned short* __restrict__ wt,
    const float* __restrict__ w0, const float* __restrict__ dep_att,
    const float* __restrict__ h_att,
    const float* __restrict__ ctx_w2, const float* __restrict__ du_a2,
    const float* __restrict__ dl_a2,
    const float* __restrict__ ctx_b2, const float* __restrict__ du_a2b,
    const float* __restrict__ dl_a2b,
    float* __restrict__ out_fdep, float* __restrict__ out_du, float* __restrict__ out_dl,
    float* __restrict__ att_sm, float* __restrict__ da_u, float* __restrict__ da_l)
{
  int bid = blockIdx.x;
  int inst = bid & 7;                 // XCD-pinned
  int n = (bid >> 3) & 1;
  int tile = bid >> 4;                // 0..47
  int ty0 = (tile / 6) * 6;           // 8 tile-rows (y step 6)
  int tx0 = (tile % 6) * 8;           // 6 tile-cols (x step 8)

  __shared__ __align__(16) unsigned short xs[80 * 256];  // 40KB swizzled halo
  __shared__ float asf[80];

  const float* asrc = (inst < 6) ? dep_att + (size_t)(inst * NB_ + n) * HW_
                    : h_att + (size_t)(((inst == 6) ? 1 : 2) * NB_ + n) * HW_;
  int nd = (inst < 6) ? 5 : (inst == 6 ? 4 : 2);
  const float* w2 = (inst < 6) ? ctx_w2 + (size_t)inst * 5 * 256
                               : (inst == 6 ? du_a2 : dl_a2);

  int t = threadIdx.x;
  const unsigned short* xg = xbf + (size_t)n * HW_ * 256;

  for (int i = t; i < 2560; i += 512) {
    int row = i >> 5, q = i & 31;
    int yy = row / 10, xx = row - yy * 10;
    int gy = ty0 + yy - 1, gx = tx0 + xx - 1;
    short8 v = (short8){0,0,0,0,0,0,0,0};
    if (gy >= 0 && gy < 48 && gx >= 0 && gx < 48)
      v = *(const short8*)(xg + ((size_t)(gy * 48 + gx)) * 256 + q * 8);
    int s = q ^ (row & 7);
    *(short8*)(xs + row * 256 + s * 8) = v;
  }
  for (int i = t; i < 80; i += 512) {
    int yy = i / 10, xx = i - yy * 10;
    int gy = ty0 + yy - 1, gx = tx0 + xx - 1;
    asf[i] = (gy >= 0 && gy < 48 && gx >= 0 && gx < 48) ? asrc[gy * 48 + gx] : 0.f;
  }
  __syncthreads();

  int wm = t >> 6;                    // wave 0..7 -> oc block wm*32
  int l = t & 63;
  int lr = l & 15, lg = l >> 4;

  f32x4 acc[2][3];
  #pragma unroll
  for (int mi = 0; mi < 2; ++mi)
    #pragma unroll
    for (int nf = 0; nf < 3; ++nf) acc[mi][nf] = (f32x4){0.f,0.f,0.f,0.f};

  int rb[3];
  #pragma unroll
  for (int nf = 0; nf < 3; ++nf) {
    int p = nf * 16 + lr;
    int y = p >> 3, x = p & 7;
    rb[nf] = y * 10 + x;
  }

  const unsigned short* wta = wt + (((size_t)inst * 72 * 16) << 9)
                              + (((size_t)(wm * 2)) << 9) + (size_t)l * 8;
  short8 av[2], nv[2];
  av[0] = *(const short8*)(wta);
  av[1] = *(const short8*)(wta + 512);

  for (int ch = 0; ch < 8; ++ch) {
    #pragma unroll
    for (int pos = 0; pos < 9; ++pos) {
      {
        int npos = (pos == 8) ? 0 : pos + 1;
        int nch = (pos == 8) ? ((ch + 1 > 7) ? 7 : ch + 1) : ch;
        size_t ofs = ((size_t)((npos * 8 + nch) * 16)) << 9;
        nv[0] = *(const short8*)(wta + ofs);
        nv[1] = *(const short8*)(wta + ofs + 512);
      }
      int koff = (pos / 3) * 10 + (pos % 3);
      short8 bfr[3];
      #pragma unroll
      for (int nf = 0; nf < 3; ++nf) {
        int rowIdx = rb[nf] + koff;
        int s = (ch * 4 + lg) ^ (rowIdx & 7);
        bfr[nf] = *(const short8*)(xs + rowIdx * 256 + s * 8);
      }
      #pragma unroll
      for (int mi = 0; mi < 2; ++mi)
        #pragma unroll
        for (int nf = 0; nf < 3; ++nf)
          acc[mi][nf] = __builtin_amdgcn_mfma_f32_16x16x32_bf16(av[mi], bfr[nf], acc[mi][nf], 0, 0, 0);
      av[0] = nv[0]; av[1] = nv[1];
    }
  }

  __syncthreads();
  float* ovl = (float*)xs;
  float* w0l = ovl;                 // 2304
  float* w2l = ovl + 2304;          // 1280
  float* sred = ovl + 3584;         // 1920
  for (int i = t; i < 2304; i += 512) w0l[i] = w0[(size_t)inst * 2304 + i];
  for (int i = t; i < 1280; i += 512) w2l[i] = (i < nd * 256) ? w2[i] : 0.f;
  __syncthreads();

  float pd[3][5];
  #pragma unroll
  for (int nf = 0; nf < 3; ++nf)
    #pragma unroll
    for (int d = 0; d < 5; ++d) pd[nf][d] = 0.f;

  #pragma unroll
  for (int nf = 0; nf < 3; ++nf) {
    #pragma unroll
    for (int mi = 0; mi < 2; ++mi) {
      #pragma unroll
      for (int r = 0; r < 4; ++r) {
        int oc = wm * 32 + mi * 16 + lg * 4 + r;
        float v = acc[mi][nf][r];
        const float* wr = &w0l[oc * 9];
        #pragma unroll
        for (int pos = 0; pos < 9; ++pos) {
          int koff = (pos / 3) * 10 + (pos % 3);
          v = fmaf(wr[pos], asf[rb[nf] + koff], v);
        }
        v = fmaxf(v, 0.f);
        #pragma unroll
        for (int d = 0; d < 5; ++d) pd[nf][d] = fmaf(w2l[d * 256 + oc], v, pd[nf][d]);
      }
    }
  }
  #pragma unroll
  for (int nf = 0; nf < 3; ++nf)
    #pragma unroll
    for (int d = 0; d < 5; ++d) {
      float s = pd[nf][d];
      s += __shfl_down(s, 32, 64);
      s += __shfl_down(s, 16, 64);
      pd[nf][d] = s;
    }
  if (lg == 0) {
    #pragma unroll
    for (int nf = 0; nf < 3; ++nf) {
      int pxi = nf * 16 + lr;
      #pragma unroll
      for (int d = 0; d < 5; ++d)
        sred[(wm * 48 + pxi) * 5 + d] = pd[nf][d];
    }
  }
  __syncthreads();
  if (t < 48) {
    int y = t >> 3, x = t & 7;
    int gk = (ty0 + y) * 48 + tx0 + x;
    float vals[5];
    float mx = -1e30f;
    for (int d = 0; d < nd; ++d) {
      float s = 0.f;
      #pragma unroll
      for (int wq = 0; wq < 8; ++wq) s += sred[(wq * 48 + t) * 5 + d];
      s += (inst < 6) ? ctx_b2[inst * 5 + d] : (inst == 6 ? du_a2b[d] : dl_a2b[d]);
      vals[d] = s;
      mx = fmaxf(mx, s);
      if (inst < 6)       out_fdep[((size_t)(inst * NB_ + n) * 5 + d) * HW_ + gk] = s;
      else if (inst == 6) out_du[((size_t)n * 4 + d) * HW_ + gk] = s;
      else                out_dl[((size_t)n * 2 + d) * HW_ + gk] = s;
    }
    float ssum = 0.f;
    for (int d = 0; d < nd; ++d) { vals[d] = expf(vals[d] - mx); ssum += vals[d]; }
    float is = 1.f / ssum;
    for (int d = 0; d < nd; ++d) {
      float sm = vals[d] * is;
      if (inst < 6)       att_sm[((size_t)(inst * NB_ + n) * 5 + d) * HW_ + gk] = sm;
      else if (inst == 6) da_u[((size_t)n * 4 + d) * HW_ + gk] = sm;
      else                da_l[((size_t)n * 2 + d) * HW_ + gk] = sm;
    }
  }
}

// ===========================================================================
// K7b: per-edge message.  ad = asrc*dsrc precomputed once in LDS.
// ===========================================================================
__global__ __launch_bounds__(256) void k_msgs_edge(
    const float* __restrict__ att_sm, const float* __restrict__ dep_att,
    const float* __restrict__ rpx, const float* __restrict__ yhv_ws,
    const float* __restrict__ dp_r1, const float* __restrict__ dp_r2,
    const float* __restrict__ dp_r2b, float* __restrict__ msg_ws)
{
  int b = blockIdx.x;
  int tile = b % 9; b /= 9;
  int n = b % NB_;  b /= NB_;
  int ui = b % 5;   int v = b / 5;
  int u = (ui < v) ? ui : ui + 1;
  int ce = (v < u) ? v : v - 1;
  int ty0 = (tile / 3) * 16, tx0 = (tile % 3) * 16;

  __shared__ float xt[10][18][20];
  __shared__ float ad[324];
  __shared__ float wl[900];
  __shared__ float w2l[100];
  __shared__ float b2l[10];
  int t = threadIdx.x;
  for (int i = t; i < 900; i += 256) {
    int d = i / 90; int rest = i - d * 90; int ic = rest / 9; int pos = rest - ic * 9;
    wl[i] = dp_r1[(d * 20 + ic) * 9 + pos];
  }
  for (int i = t; i < 100; i += 256) w2l[i] = dp_r2[i];
  if (t < 10) b2l[t] = dp_r2b[t];

  const float* asrc = att_sm + ((size_t)(u * NB_ + n) * 5 + ce) * HW_;
  const float* dsrc = dep_att + (size_t)(u * NB_ + n) * HW_;
  for (int i = t; i < 324; i += 256) {
    int rr = i / 18, cc = i - (i / 18) * 18;
    int gy = ty0 + rr - 1, gx = tx0 + cc - 1;
    float val = 0.f;
    if (gy >= 0 && gy < 48 && gx >= 0 && gx < 48) {
      int kk = gy * 48 + gx;
      val = asrc[kk] * dsrc[kk];
    }
    ad[i] = val;
  }
  __syncthreads();
  for (int i = t; i < 10 * 324; i += 256) {
    int d = i / 324; int r = i - d * 324; int rr = r / 18; int cc = r - rr * 18;
    int gy = ty0 + rr - 1, gx = tx0 + cc - 1;
    float val = 0.f;
    if (gy >= 0 && gy < 48 && gx >= 0 && gx < 48) {
      int kk = gy * 48 + gx;
      val = ad[r] * rpx[((size_t)n * 10 + d) * HW_ + kk];
    }
    xt[d][rr][cc] = val;
  }
  __syncthreads();
  int rr = t >> 4, cc = t & 15;
  int k = (ty0 + rr) * 48 + tx0 + cc;
  float y[10];
  #pragma unroll
  for (int d = 0; d < 10; ++d) y[d] = 0.f;
  for (int ic = 0; ic < 10; ++ic)
    #pragma unroll
    for (int kh = 0; kh < 3; ++kh)
      #pragma unroll
      for (int kw = 0; kw < 3; ++kw) {
        float xv = xt[ic][rr + kh][cc + kw];
        #pragma unroll
        for (int d = 0; d < 10; ++d)
          y[d] = fmaf(wl[(d * 10 + ic) * 9 + kh * 3 + kw], xv, y[d]);
      }
  float s[10];
  #pragma unroll
  for (int d = 0; d < 10; ++d)
    s[d] = fmaxf(y[d] + yhv_ws[((size_t)(v * NB_ + n) * 10 + d) * HW_ + k], 0.f);
  #pragma unroll
  for (int d = 0; d < 10; ++d) {
    float m = b2l[d];
    #pragma unroll
    for (int j = 0; j < 10; ++j) m = fmaf(w2l[d * 10 + j], s[j], m);
    msg_ws[(((size_t)(v * 5 + ui) * NB_ + n) * 10 + d) * HW_ + k] = sigmoidf_(m);
  }
}

// ===========================================================================
// K8: parts conv + alpha*sum(msgs) + GRU (nodes 0..6).  dp = da*patt cached.
// ===========================================================================
__global__ __launch_bounds__(256) void k_parts_gru(
    const float* __restrict__ h_nodes, const float* __restrict__ p_nodes,
    const float* __restrict__ h_att,
    const float* __restrict__ da_u, const float* __restrict__ da_l,
    const float* __restrict__ du_r1, const float* __restrict__ du_r2,
    const float* __restrict__ dl_r1, const float* __restrict__ dl_r2,
    const float* __restrict__ msg_ws, const float* __restrict__ alpha,
    const float* __restrict__ gru_gw, const float* __restrict__ gru_gb,
    const float* __restrict__ gru_cw, float* __restrict__ p_new)
{
  int b = blockIdx.x;
  int tile = b % 9; b /= 9;
  int n = b % NB_;  int vp = b / NB_;   // 0..6
  int ty0 = (tile / 3) * 16, tx0 = (tile % 3) * 16;
  int t = threadIdx.x;
  int rr = t >> 4, cc = t & 15;
  int k = (ty0 + rr) * 48 + tx0 + cc;

  float x[10], h[10];

  if (vp == 0) {
    #pragma unroll
    for (int d = 0; d < 10; ++d) {
      x[d] = h_nodes[((size_t)n * 10 + d) * HW_ + k];
      h[d] = p_nodes[((size_t)n * 10 + d) * HW_ + k];
    }
  } else {
    bool isU = (vp <= 4);
    int j = isU ? vp - 1 : vp - 5;
    const float* parent = h_nodes + ((size_t)((isU ? 1 : 2) * NB_ + n) * 10) * HW_;
    const float* patt   = h_att + (size_t)((isU ? 1 : 2) * NB_ + n) * HW_;
    const float* da     = isU ? (da_u + ((size_t)n * 4 + j) * HW_) : (da_l + ((size_t)n * 2 + j) * HW_);
    const float* child  = p_nodes + (size_t)(vp * NB_ + n) * 10 * HW_;
    const float* r1 = isU ? du_r1 : dl_r1;
    const float* r2 = isU ? du_r2 : dl_r2;

    __shared__ float xt[20][18][20];
    __shared__ float dpl[324];
    __shared__ float wl[1800];
    __shared__ float w2l[100];
    for (int i = t; i < 1800; i += 256) wl[i] = r1[i];
    for (int i = t; i < 100; i += 256) w2l[i] = r2[i];
    for (int i = t; i < 324; i += 256) {
      int r2i = i / 18, c2 = i - (i / 18) * 18;
      int gy = ty0 + r2i - 1, gx = tx0 + c2 - 1;
      float val = 0.f;
      if (gy >= 0 && gy < 48 && gx >= 0 && gx < 48) {
        int kk = gy * 48 + gx;
        val = da[kk] * patt[kk];
      }
      dpl[i] = val;
    }
    __syncthreads();
    for (int i = t; i < 20 * 324; i += 256) {
      int d = i / 324; int r = i - d * 324; int r2i = r / 18; int c2 = r - r2i * 18;
      int gy = ty0 + r2i - 1, gx = tx0 + c2 - 1;
      float val = 0.f;
      if (gy >= 0 && gy < 48 && gx >= 0 && gx < 48) {
        int kk = gy * 48 + gx;
        val = (d < 10) ? parent[(size_t)d * HW_ + kk] * dpl[r]
                       : child[(size_t)(d - 10) * HW_ + kk];
      }
      xt[d][r2i][c2] = val;
    }
    __syncthreads();
    float y[10];
    #pragma unroll
    for (int d = 0; d < 10; ++d) y[d] = 0.f;
    for (int ic = 0; ic < 20; ++ic)
      #pragma unroll
      for (int kh = 0; kh < 3; ++kh)
        #pragma unroll
        for (int kw = 0; kw < 3; ++kw) {
          float xv = xt[ic][rr + kh][cc + kw];
          #pragma unroll
          for (int d = 0; d < 10; ++d)
            y[d] = fmaf(wl[(d * 20 + ic) * 9 + kh * 3 + kw], xv, y[d]);
        }
    float yr[10];
    #pragma unroll
    for (int d = 0; d < 10; ++d) yr[d] = fmaxf(y[d], 0.f);

    float al = alpha[0];
    int v = vp - 1;
    #pragma unroll
    for (int d = 0; d < 10; ++d) {
      float s = 0.f;
      #pragma unroll
      for (int jj = 0; jj < 10; ++jj) s = fmaf(w2l[d * 10 + jj], yr[jj], s);
      float parts = fmaxf(s, 0.f);
      float xs = 0.f;
      #pragma unroll
      for (int ui = 0; ui < 5; ++ui)
        xs += msg_ws[(((size_t)(v * 5 + ui) * NB_ + n) * 10 + d) * HW_ + k];
      x[d] = parts + al * xs;
      h[d] = p_nodes[((size_t)(vp * NB_ + n) * 10 + d) * HW_ + k];
    }
  }

  const float* gw = gru_gw + (size_t)vp * 40;
  const float* gb = gru_gb + (size_t)vp * 2;
  const float* cw = gru_cw + (size_t)vp * 200;
  float g0 = gb[0], g1 = gb[1];
  #pragma unroll
  for (int d = 0; d < 10; ++d) {
    g0 = fmaf(gw[d], x[d], fmaf(gw[10 + d], h[d], g0));
    g1 = fmaf(gw[20 + d], x[d], fmaf(gw[30 + d], h[d], g1));
  }
  float rg = sigmoidf_(g0);
  float ug = sigmoidf_(g1);
  #pragma unroll
  for (int d = 0; d < 10; ++d) {
    float s = 0.f;
    const float* cr = cw + d * 20;
    #pragma unroll
    for (int jj = 0; jj < 10; ++jj)
      s = fmaf(cr[jj], x[jj], fmaf(cr[10 + jj], rg * h[jj], s));
    float cn = fmaxf(s, 0.f);
    p_new[((size_t)(vp * NB_ + n) * 10 + d) * HW_ + k] = (1.f - ug) * h[d] + ug * cn;
  }
}

// ---------------------------------------------------------------------------
extern "C" void kernel_launch(void* const* d_in, const int* in_sizes, int n_in,
                              void* d_out, int out_size, void* d_ws, size_t ws_size,
                              hipStream_t stream) {
  (void)in_sizes; (void)n_in; (void)out_size; (void)ws_size;
  const float* h_nodes = (const float*)d_in[1];
  const float* p_nodes = (const float*)d_in[2];
  const float* xp      = (const float*)d_in[3];
  const float* h_att   = (const float*)d_in[4];
  const float* p_att   = (const float*)d_in[5];
  const float* dc_q_w  = (const float*)d_in[6];
  const float* dc_q_b  = (const float*)d_in[7];
  const float* dc_k_w  = (const float*)d_in[8];
  const float* dc_k_b  = (const float*)d_in[9];
  const float* dc_p_w  = (const float*)d_in[10];
  const float* dc_p_b  = (const float*)d_in[11];
  const float* ctx_w1  = (const float*)d_in[12];
  const float* ctx_w2  = (const float*)d_in[13];
  const float* ctx_b2  = (const float*)d_in[14];
  const float* du_a1   = (const float*)d_in[15];
  const float* du_a2   = (const float*)d_in[16];
  const float* du_a2b  = (const float*)d_in[17];
  const float* du_r1   = (const float*)d_in[18];
  const float* du_r2   = (const float*)d_in[19];
  const float* dl_a1   = (const float*)d_in[20];
  const float* dl_a2   = (const float*)d_in[21];
  const float* dl_a2b  = (const float*)d_in[22];
  const float* dl_r1   = (const float*)d_in[23];
  const float* dl_r2   = (const float*)d_in[24];
  const float* dp_proj = (const float*)d_in[25];
  const float* dp_r1   = (const float*)d_in[26];
  const float* dp_r2   = (const float*)d_in[27];
  const float* dp_r2b  = (const float*)d_in[28];
  const float* gru_gw  = (const float*)d_in[29];
  const float* gru_gb  = (const float*)d_in[30];
  const float* gru_cw  = (const float*)d_in[31];
  const float* alpha   = (const float*)d_in[32];

  float* ws = (float*)d_ws;
  float* qdot    = ws + 4608;          // 16
  float* dep_att = ws + 4624;          // 27648
  float* rpx     = ws + 32272;         // 46080
  float* att_sm  = ws + 78352;         // 138240
  float* da_u    = ws + 216592;        // 18432
  float* da_l    = ws + 235024;        // 9216
  float* yhv_ws  = ws + 244240;        // 276480
  float* w0      = ws + 520720;        // 18432 -> floats end at 539152
  float* hu_ws   = att_sm + 27648;     // alias (dead until k_convfused)
  unsigned short* us = (unsigned short*)(ws + 539152);
  unsigned short* xbf = us;                       // 1,179,648 shorts
  unsigned short* wt  = us + 1179648;             // 4,718,592 shorts
  float* msg_ws = (float*)(us + 5898240);         // 1,382,400 floats

  float* out      = (float*)d_out;
  float* out_pnew = out;               // 322560
  float* out_du   = out + 322560;      // 18432
  float* out_dl   = out + 340992;      // 9216
  float* out_fdep = out + 350208;      // 138240

  k_fa<<<2612, 256, 0, stream>>>(xp, xbf, ctx_w1, du_a1, dl_a1, wt, w0,
                                 p_att, hu_ws, p_nodes, dp_r1, yhv_ws);
  k_fb<<<84, 256, 0, stream>>>(p_att, hu_ws, dc_q_w, dc_q_b, dc_p_w, qdot,
                               xbf, dp_proj, rpx);
  k_keymma<<<72, 256, 0, stream>>>(xbf, dc_k_w, dc_k_b, dc_p_w,
                                   qdot, dc_p_b, p_att, dep_att);
  k_convfused<<<768, 512, 0, stream>>>(xbf, wt, w0, dep_att, h_att,
                                       ctx_w2, du_a2, dl_a2, ctx_b2, du_a2b, dl_a2b,
                                       out_fdep, out_du, out_dl, att_sm, da_u, da_l);
  k_msgs_edge<<<540, 256, 0, stream>>>(att_sm, dep_att, rpx, yhv_ws,
                                       dp_r1, dp_r2, dp_r2b, msg_ws);
  k_parts_gru<<<126, 256, 0, stream>>>(h_nodes, p_nodes, h_att, da_u, da_l,
                                       du_r1, du_r2, dl_r1, dl_r2, msg_ws, alpha,
                                       gru_gw, gru_gb, gru_cw, out_pnew);
}